// Round 11
// baseline (1954.082 us; speedup 1.0000x reference)
//
#include <hip/hip_runtime.h>
#include <hip/hip_bf16.h>

// Problem constants
#define B_  64
#define T_  512
#define E_  256
#define H_  512
#define G4_ 2048
#define C_  4

typedef __attribute__((ext_vector_type(4))) float  f32x4;
typedef __attribute__((ext_vector_type(8))) __bf16 bf16x8;
typedef __attribute__((ext_vector_type(8))) short  short8;   // no HIP builtin 'short8'
typedef __attribute__((ext_vector_type(4))) short  s16x4;    // HIP predefines 'short4'

union V16 { f32x4 f; bf16x8 b; short8 s; };

__device__ __forceinline__ float sigmoid_(float x) { return 1.0f / (1.0f + __expf(-x)); }
__device__ __forceinline__ float tanh_(float x)    { return 1.0f - 2.0f / (__expf(2.0f * x) + 1.0f); }

// Deterministic RNE fp32 -> bf16
__device__ __forceinline__ short f2bf(float f) {
  union { float f; unsigned u; } v; v.f = f;
  return (short)((v.u + 0x7FFFu + ((v.u >> 16) & 1u)) >> 16);
}

// --- per-access MALL-coherent ops (sc0 sc1 = bypass L1+L2, coherent point) ---
__device__ __forceinline__ void store_short_llc(void* p, unsigned v) {
  asm volatile("global_store_short %0, %1, off sc0 sc1" :: "v"(p), "v"(v) : "memory");
}
__device__ __forceinline__ void store_dword_llc(void* p, float v) {
  asm volatile("global_store_dword %0, %1, off sc0 sc1" :: "v"(p), "v"(v) : "memory");
}
__device__ __forceinline__ void store_dwordx2_llc(void* p, s16x4 v) {
  asm volatile("global_store_dwordx2 %0, %1, off sc0 sc1" :: "v"(p), "v"(v) : "memory");
}
__device__ __forceinline__ f32x4 ld_b128_llc(const void* p) {
  f32x4 v;
  asm volatile("global_load_dwordx4 %0, %1, off sc0 sc1\n\ts_waitcnt vmcnt(0)"
               : "=&v"(v) : "v"(p) : "memory");
  return v;
}
// Fire-and-forget coherent xg prefetch: retired by the NEXT vmcnt(0) (the
// staging load) — consumed two barriers later. r8-proven mechanism.
__device__ __forceinline__ void prefetch_xg_llc(const short* p,
                                                unsigned* r0, unsigned* r1,
                                                unsigned* r2, unsigned* r3) {
  asm volatile(
      "global_load_ushort %0, %4, off sc0 sc1\n\t"
      "global_load_ushort %1, %5, off sc0 sc1\n\t"
      "global_load_ushort %2, %6, off sc0 sc1\n\t"
      "global_load_ushort %3, %7, off sc0 sc1"
      : "=&v"(*r0), "=&v"(*r1), "=&v"(*r2), "=&v"(*r3)
      : "v"(p), "v"(p + 32768), "v"(p + 65536), "v"(p + 98304)
      : "memory");
}

// ---------------------------------------------------------------------------
// One-time W_ih fp32 -> bf16 converter (r9 win; tiny serial kernel).
// ---------------------------------------------------------------------------
__global__ __launch_bounds__(256, 1) void wih_conv(const float* __restrict__ W,
                                                   short* __restrict__ out) {
  const int i = (blockIdx.x * 256 + threadIdx.x) * 4;
  f32x4 v = *(const f32x4*)(W + i);
  s16x4 s;
  s[0] = f2bf(v[0]); s[1] = f2bf(v[1]); s[2] = f2bf(v[2]); s[3] = f2bf(v[3]);
  *(s16x4*)(out + i) = s;
}

// ---------------------------------------------------------------------------
// FUSED kernel: 576 blocks x 512 threads.
//   blk <  64 : lstm role — VERBATIM r10 loop (8x8 groups, thin pollers, LDS
//               stage, 4 barriers) + lane-8 xgflag poll + post-S1 coherent xg
//               prefetch (replaces the pre-poll plain loads).
//   blk >= 64 : xg role — t = blk-64; r10 xg body re-waved for 512 thr
//               (wave wv: gate wv&3, mt half wv>>2); sc0sc1 write-through
//               stores + drain + xgflag[t] publish.
// Safety: xg blocks have no dependencies (drain under any dispatch order);
// 64 lstm blocks always fit on 256 CUs; all cross-role traffic meets at the
// MALL (no same-dispatch L2 staleness).
// ---------------------------------------------------------------------------
union SMem {
  struct { int idx[B_]; short e[B_][E_ + 8]; } xg;          // 34 KB
  struct { short h[16][520]; float pre[4][8][68]; } lstm;   // 25 KB
};

template<bool WBF16>
__global__ __launch_bounds__(512, 2) void fused_kernel(
    const int* __restrict__ x, const float* __restrict__ emb,
    const void* __restrict__ Wv,
    const float* __restrict__ W_hh,
    const float* __restrict__ b_ih, const float* __restrict__ b_hh,
    const float* __restrict__ W_fc, const float* __restrict__ b_fc,
    unsigned int* ctl, __hip_bfloat16* hbuf /*[2][64][512]*/, float* hT,
    __hip_bfloat16* xgbuf, float* out)
{
  __shared__ SMem sm;
  const int tid  = threadIdx.x;
  const int blk  = blockIdx.x;
  const int wv   = tid >> 6;
  const int lane = tid & 63;
  const int ln15 = lane & 15, quad = lane >> 4;

  if (blk >= 64) {
    // ------------------------- xg role: one t-slice -------------------------
    const int t = blk - 64;
    if (tid < B_) sm.xg.idx[tid] = x[tid * T_ + t];
    __syncthreads();
    {
      int b = tid >> 3, ch = tid & 7;                    // 32 elems per thread
      const float* src = emb + (size_t)sm.xg.idx[b] * E_ + ch * 32;
      short* dst = &sm.xg.e[b][ch * 32];
#pragma unroll
      for (int i = 0; i < 8; i++) {
        f32x4 v = *(const f32x4*)(src + i * 4);
        s16x4 s;
        s[0] = f2bf(v[0]); s[1] = f2bf(v[1]); s[2] = f2bf(v[2]); s[3] = f2bf(v[3]);
        *(s16x4*)(dst + i * 4) = s;
      }
    }
    __syncthreads();

    V16 breg[4][8];
#pragma unroll
    for (int nt = 0; nt < 4; nt++)
#pragma unroll
      for (int ks = 0; ks < 8; ks++)
        breg[nt][ks].f = *(const f32x4*)(&sm.xg.e[nt * 16 + ln15][quad * 8 + ks * 32]);

    const int gw  = wv & 3;                  // gate group
    const int mt0 = (wv >> 2) * 16;          // mt half
    const int gbase = gw * 512;
    const size_t base_t = (size_t)t * (G4_ * B_);
    for (int mt = mt0; mt < mt0 + 16; mt++) {
      const int grow = gbase + mt * 16 + ln15;
      V16 areg[8];
      if constexpr (WBF16) {
        const short* arow = (const short*)Wv + (size_t)grow * E_ + quad * 8;
#pragma unroll
        for (int ks = 0; ks < 8; ks++)
          areg[ks].f = *(const f32x4*)(arow + ks * 32);
      } else {
        const float* arow = (const float*)Wv + (size_t)grow * E_ + quad * 8;
#pragma unroll
        for (int ks = 0; ks < 8; ks++) {
          f32x4 lo = *(const f32x4*)(arow + ks * 32);
          f32x4 hi = *(const f32x4*)(arow + ks * 32 + 4);
          short8 s;
          s[0] = f2bf(lo[0]); s[1] = f2bf(lo[1]); s[2] = f2bf(lo[2]); s[3] = f2bf(lo[3]);
          s[4] = f2bf(hi[0]); s[5] = f2bf(hi[1]); s[6] = f2bf(hi[2]); s[7] = f2bf(hi[3]);
          areg[ks].s = s;
        }
      }

      f32x4 acc[4];
#pragma unroll
      for (int nt = 0; nt < 4; nt++) acc[nt] = (f32x4){0.f, 0.f, 0.f, 0.f};
#pragma unroll
      for (int ks = 0; ks < 8; ks++)
#pragma unroll
        for (int nt = 0; nt < 4; nt++)
          acc[nt] = __builtin_amdgcn_mfma_f32_16x16x32_bf16(areg[ks].b, breg[nt][ks].b, acc[nt], 0, 0, 0);

      const int dbase = mt * 16 + quad * 4;
#pragma unroll
      for (int nt = 0; nt < 4; nt++) {
        const int batch = nt * 16 + ln15;
        s16x4 sv;
#pragma unroll
        for (int r = 0; r < 4; r++) sv[r] = f2bf(acc[nt][r]);
        store_dwordx2_llc((short*)xgbuf + base_t + ((size_t)gw << 15) +
                          ((size_t)batch << 9) + dbase, sv);
      }
    }
    // Publish: per-thread drain (stores acked at MALL), join, one flag.
    asm volatile("s_waitcnt vmcnt(0)" ::: "memory");
    __syncthreads();
    if (tid == 0)
      __hip_atomic_store(ctl + 256 + t, 1u, __ATOMIC_RELAXED, __HIP_MEMORY_SCOPE_AGENT);
    return;
  }

  // --------------------------- lstm role (r10) ----------------------------
  const int g    = blk & 7;        // batch group (8 batches)
  const int pd   = blk >> 3;       // dim slice [pd*64, +64)
  const int d0   = pd * 64;

  // Register-resident bf16 A fragments (two M-tiles per wave).
  const int gate  = wv >> 1;
  const int dhalf = (wv & 1) * 32;
  V16 areg[2][16];
#pragma unroll
  for (int tau = 0; tau < 2; tau++) {
    const int grow = gate * 512 + d0 + dhalf + tau * 16 + ln15;
    const float* ap = W_hh + (size_t)grow * H_ + quad * 8;
#pragma unroll
    for (int ks = 0; ks < 16; ks++) {
      f32x4 lo = *(const f32x4*)(ap + ks * 32);
      f32x4 hi = *(const f32x4*)(ap + ks * 32 + 4);
      short8 s;
      s[0] = f2bf(lo[0]); s[1] = f2bf(lo[1]); s[2] = f2bf(lo[2]); s[3] = f2bf(lo[3]);
      s[4] = f2bf(hi[0]); s[5] = f2bf(hi[1]); s[6] = f2bf(hi[2]); s[7] = f2bf(hi[3]);
      areg[tau][ks].s = s;
    }
  }

  const int nb = tid >> 6;         // 0..7 (== wv)
  const int nd = tid & 63;         // 0..63
  const int gb = g * 8 + nb;       // global batch
  const int dg = d0 + nd;          // global h-dim
  const float bias_i = b_ih[dg]        + b_hh[dg];
  const float bias_f = b_ih[512 + dg]  + b_hh[512 + dg];
  const float bias_g = b_ih[1024 + dg] + b_hh[1024 + dg];
  const float bias_o = b_ih[1536 + dg] + b_hh[1536 + dg];
  float c = 0.0f;
  const int myflag = g * 16 + pd;
  const short* xg_s = (const short*)xgbuf;

  // zero s_h rows 8..15 once (zero-padded N cols); first S2 orders it.
  *(f32x4*)&sm.lstm.h[8 + (tid >> 6)][(tid & 63) * 8] = (f32x4){0.f, 0.f, 0.f, 0.f};

  for (int t = 0; t < T_; t++) {
    const int cur = t & 1, nxt = cur ^ 1;

    // Thin poll: lanes 0-7 wait on our group's 8 h flags; lane 8 waits on
    // this step's xg slice.
    if (tid < 8) {
      const unsigned* fp = ctl + g * 16 + tid;
      while (__hip_atomic_load(fp, __ATOMIC_RELAXED, __HIP_MEMORY_SCOPE_AGENT) < (unsigned)t) {}
    } else if (tid == 8) {
      while (__hip_atomic_load(ctl + 256 + t, __ATOMIC_RELAXED, __HIP_MEMORY_SCOPE_AGENT) == 0u) {}
    }
    __syncthreads();   // S1: h_t and xg[t] visible

    // xg prefetch: coherent fire-and-forget; retired by the staging vmcnt(0).
    unsigned px0, px1, px2, px3;
    prefetch_xg_llc(xg_s + (size_t)t * (G4_ * B_) + ((size_t)gb << 9) + dg,
                    &px0, &px1, &px2, &px3);

    // Stage h_t -> LDS: 8 KB via 1 coherent 16B load/thread, coalesced.
    {
      const short* hbase = (const short*)hbuf + (size_t)cur * (B_ * H_) + (size_t)(g * 8) * H_;
      f32x4 va = ld_b128_llc(hbase + tid * 8);
      *(f32x4*)&sm.lstm.h[tid >> 6][(tid & 63) * 8] = va;
    }
    __syncthreads();   // S2: LDS staging complete

    // 32 MFMAs on 2 chains, breg shared across the wave's two M-tiles.
    f32x4 acc0 = (f32x4){0.f, 0.f, 0.f, 0.f};
    f32x4 acc1 = (f32x4){0.f, 0.f, 0.f, 0.f};
#pragma unroll
    for (int ks = 0; ks < 16; ks++) {
      V16 b0;
      b0.f = *(const f32x4*)&sm.lstm.h[ln15][quad * 8 + ks * 32];
      acc0 = __builtin_amdgcn_mfma_f32_16x16x32_bf16(areg[0][ks].b, b0.b, acc0, 0, 0, 0);
      acc1 = __builtin_amdgcn_mfma_f32_16x16x32_bf16(areg[1][ks].b, b0.b, acc1, 0, 0, 0);
    }

    if (ln15 < 8) {
      *(f32x4*)&sm.lstm.pre[gate][ln15][dhalf + quad * 4]      = acc0;
      *(f32x4*)&sm.lstm.pre[gate][ln15][dhalf + 16 + quad * 4] = acc1;
    }
    __syncthreads();   // S3: preactivations complete

    {
      const float pi = sm.lstm.pre[0][nb][nd] + bias_i + __uint_as_float(px0 << 16);
      const float pf = sm.lstm.pre[1][nb][nd] + bias_f + __uint_as_float(px1 << 16);
      const float pg = sm.lstm.pre[2][nb][nd] + bias_g + __uint_as_float(px2 << 16);
      const float po = sm.lstm.pre[3][nb][nd] + bias_o + __uint_as_float(px3 << 16);
      const float i_ = sigmoid_(pi), f_ = sigmoid_(pf);
      const float g_ = tanh_(pg),    o_ = sigmoid_(po);
      c = f_ * c + i_ * g_;
      const float h = o_ * tanh_(c);
      if (t < T_ - 1) {
        store_short_llc((short*)hbuf + (size_t)nxt * (B_ * H_) + (size_t)gb * H_ + dg,
                        (unsigned)(unsigned short)f2bf(h));
      } else {
        store_dword_llc(hT + gb * H_ + dg, h);
      }
    }
    __syncthreads();   // S4: vmcnt(0) drain -> h stores acked at MALL

    if (tid == 0)
      __hip_atomic_store(ctl + myflag, (unsigned)(t + 1),
                         __ATOMIC_RELAXED, __HIP_MEMORY_SCOPE_AGENT);
  }

  // Phase 3: fp32 FC by block 0 (poll all 64 block flags == T)
  if (blk == 0) {
    if (tid < 64)
      while (__hip_atomic_load(ctl + (tid >> 3) * 16 + (tid & 7),
                               __ATOMIC_RELAXED, __HIP_MEMORY_SCOPE_AGENT) < (unsigned)T_) {}
    __builtin_amdgcn_fence(__ATOMIC_ACQUIRE, "agent");
    __syncthreads();
    for (int o = tid; o < B_ * C_; o += 512) {
      const int b = o >> 2, cl = o & 3;
      const f32x4* hr = (const f32x4*)(hT + b * H_);
      const f32x4* wr = (const f32x4*)(W_fc + cl * H_);
      float s = 0.f;
      for (int d4 = 0; d4 < H_ / 4; d4++) {
        const f32x4 hv = hr[d4];
        const f32x4 wv4 = wr[d4];
        s += hv[0] * wv4[0] + hv[1] * wv4[1] + hv[2] * wv4[2] + hv[3] * wv4[3];
      }
      s += b_fc[cl];
      out[o] = s;
    }
  }
}

// ---------------------------------------------------------------------------
// Workspace map:
//   [0, 1024)            : ctl h-flags (group g's 8 flags at words [g*16,+8))
//   [1024, 3072)         : ctl xg flags[512] (word offset 256)
//   [4096, 135168)       : hbuf[2][64][512] bf16 (zeroed = h0)
//   [135168, 266240)     : hT[64][512] fp32
//   [524288, 134742016)  : xg[T][4][B][512] bf16 (128 MiB; flag-gated, no memset)
//   [134742016, 135790592): W_ih bf16 table (1 MiB) — only if ws_size allows
// ---------------------------------------------------------------------------
extern "C" void kernel_launch(void* const* d_in, const int* in_sizes, int n_in,
                              void* d_out, int out_size, void* d_ws, size_t ws_size,
                              hipStream_t stream) {
  const int*   x    = (const int*)d_in[0];
  const float* emb  = (const float*)d_in[1];
  const float* W_ih = (const float*)d_in[2];
  const float* W_hh = (const float*)d_in[3];
  const float* b_ih = (const float*)d_in[4];
  const float* b_hh = (const float*)d_in[5];
  const float* W_fc = (const float*)d_in[6];
  const float* b_fc = (const float*)d_in[7];
  float* out = (float*)d_out;

  char* ws = (char*)d_ws;
  const size_t XG_OFF  = 524288;
  const size_t XG_END  = XG_OFF + (size_t)T_ * G4_ * B_ * 2;   // 134,742,016
  const size_t NEEDED2 = XG_END + (size_t)G4_ * E_ * 2;        // +1 MiB bf16 W_ih
  if (ws_size < XG_END) return;

  unsigned int*   ctl   = (unsigned int*)ws;
  __hip_bfloat16* hbuf  = (__hip_bfloat16*)(ws + 4096);
  float*          hT    = (float*)(ws + 135168);
  __hip_bfloat16* xgbuf = (__hip_bfloat16*)(ws + XG_OFF);
  short*          wih16 = (short*)(ws + XG_END);

  (void)hipMemsetAsync(ws, 0, 135168, stream);   // ctl + hbuf

  if (ws_size >= NEEDED2) {
    wih_conv<<<512, 256, 0, stream>>>(W_ih, wih16);
    fused_kernel<true><<<576, 512, 0, stream>>>(
        x, emb, wih16, W_hh, b_ih, b_hh, W_fc, b_fc, ctl, hbuf, hT, xgbuf, out);
  } else {
    fused_kernel<false><<<576, 512, 0, stream>>>(
        x, emb, W_ih, W_hh, b_ih, b_hh, W_fc, b_fc, ctl, hbuf, hT, xgbuf, out);
  }
}

// Round 12
// 1510.963 us; speedup vs baseline: 1.2933x; 1.2933x over previous
//
#include <hip/hip_runtime.h>
#include <hip/hip_bf16.h>

// Problem constants
#define B_  64
#define T_  512
#define E_  256
#define H_  512
#define G4_ 2048
#define C_  4

typedef __attribute__((ext_vector_type(4))) float  f32x4;
typedef __attribute__((ext_vector_type(8))) __bf16 bf16x8;
typedef __attribute__((ext_vector_type(8))) short  short8;   // no HIP builtin 'short8'
typedef __attribute__((ext_vector_type(4))) short  s16x4;    // HIP predefines 'short4'

union V16 { f32x4 f; bf16x8 b; short8 s; };

__device__ __forceinline__ float sigmoid_(float x) { return 1.0f / (1.0f + __expf(-x)); }
__device__ __forceinline__ float tanh_(float x)    { return 1.0f - 2.0f / (__expf(2.0f * x) + 1.0f); }

// Deterministic RNE fp32 -> bf16
__device__ __forceinline__ short f2bf(float f) {
  union { float f; unsigned u; } v; v.f = f;
  return (short)((v.u + 0x7FFFu + ((v.u >> 16) & 1u)) >> 16);
}

// --- per-access MALL-coherent ops (sc0 sc1 = bypass L1+L2, coherent point) ---
__device__ __forceinline__ void store_short_llc(void* p, unsigned v) {
  asm volatile("global_store_short %0, %1, off sc0 sc1" :: "v"(p), "v"(v) : "memory");
}
__device__ __forceinline__ void store_dword_llc(void* p, float v) {
  asm volatile("global_store_dword %0, %1, off sc0 sc1" :: "v"(p), "v"(v) : "memory");
}
// one coherent 16B load + drain (staging)
__device__ __forceinline__ f32x4 ld_b128_llc(const void* p) {
  f32x4 v;
  asm volatile("global_load_dwordx4 %0, %1, off sc0 sc1\n\ts_waitcnt vmcnt(0)"
               : "=&v"(v) : "v"(p) : "memory");
  return v;
}

// ---------------------------------------------------------------------------
// One-time W_ih fp32 -> bf16 converter (r9 win).
// ---------------------------------------------------------------------------
__global__ __launch_bounds__(256, 1) void wih_conv(const float* __restrict__ W,
                                                   short* __restrict__ out) {
  const int i = (blockIdx.x * 256 + threadIdx.x) * 4;   // grid 512 -> 524288 elems
  f32x4 v = *(const f32x4*)(W + i);
  s16x4 s;
  s[0] = f2bf(v[0]); s[1] = f2bf(v[1]); s[2] = f2bf(v[2]); s[3] = f2bf(v[3]);
  *(s16x4*)(out + i) = s;
}

// ---------------------------------------------------------------------------
// Phase 1: xg[t][g][b][d] = (emb[x[b][t]] @ W_ih^T)[g*512+d]  (bias added later)
// r12 change: A-fragment DOUBLE BUFFER — mt+1's 8 L2 loads issue before mt's
// 32 MFMAs, hiding the ~200-cyc L2 latency chain that made r10's xg ~12%
// MFMA-util. bf16-weight path only (fp32 fallback kept, unpipelined).
// ---------------------------------------------------------------------------
template<bool WBF16>
__global__ __launch_bounds__(256, 1) void xg_kernel(
    const int* __restrict__ x, const float* __restrict__ emb,
    const void* __restrict__ Wv,
    __hip_bfloat16* __restrict__ xg)
{
  const int t   = blockIdx.x;
  const int tid = threadIdx.x;
  __shared__ int s_idx[B_];
  __shared__ __hip_bfloat16 s_e[B_][E_ + 8];

  if (tid < B_) s_idx[tid] = x[tid * T_ + t];
  __syncthreads();
  {
    int b = tid >> 2, ch = tid & 3;
    const float* src = emb + (size_t)s_idx[b] * E_ + ch * 64;
    short* dst = (short*)&s_e[b][ch * 64];
#pragma unroll
    for (int i = 0; i < 16; i++) {
      f32x4 v = *(const f32x4*)(src + i * 4);
      s16x4 s;
      s[0] = f2bf(v[0]); s[1] = f2bf(v[1]); s[2] = f2bf(v[2]); s[3] = f2bf(v[3]);
      *(s16x4*)(dst + i * 4) = s;
    }
  }
  __syncthreads();

  const int wv   = tid >> 6;
  const int lane = tid & 63;
  const int ln15 = lane & 15, quad = lane >> 4;

  V16 breg[4][8];
#pragma unroll
  for (int nt = 0; nt < 4; nt++)
#pragma unroll
    for (int ks = 0; ks < 8; ks++)
      breg[nt][ks].f = *(const f32x4*)(&s_e[nt * 16 + ln15][quad * 8 + ks * 32]);

  const int gbase = wv * 512;
  const size_t base_t = (size_t)t * (G4_ * B_);

  if constexpr (WBF16) {
    const short* W16 = (const short*)Wv;
    V16 areg[2][8];
    {
      const short* arow = W16 + (size_t)(gbase + ln15) * E_ + quad * 8;
#pragma unroll
      for (int ks = 0; ks < 8; ks++)
        areg[0][ks].f = *(const f32x4*)(arow + ks * 32);
    }
    for (int mt = 0; mt < 32; mt++) {
      const int cb = mt & 1;
      if (mt < 31) {   // prefetch next M-tile's fragments (overlaps MFMAs below)
        const short* arow = W16 + (size_t)(gbase + (mt + 1) * 16 + ln15) * E_ + quad * 8;
#pragma unroll
        for (int ks = 0; ks < 8; ks++)
          areg[cb ^ 1][ks].f = *(const f32x4*)(arow + ks * 32);
      }

      f32x4 acc[4];
#pragma unroll
      for (int nt = 0; nt < 4; nt++) acc[nt] = (f32x4){0.f, 0.f, 0.f, 0.f};
#pragma unroll
      for (int ks = 0; ks < 8; ks++)
#pragma unroll
        for (int nt = 0; nt < 4; nt++)
          acc[nt] = __builtin_amdgcn_mfma_f32_16x16x32_bf16(areg[cb][ks].b, breg[nt][ks].b, acc[nt], 0, 0, 0);

      const int dbase = mt * 16 + quad * 4;
#pragma unroll
      for (int nt = 0; nt < 4; nt++) {
        const int batch = nt * 16 + ln15;
        s16x4 sv;
#pragma unroll
        for (int r = 0; r < 4; r++) sv[r] = f2bf(acc[nt][r]);
        *(s16x4*)((short*)xg + base_t + ((size_t)wv << 15) + ((size_t)batch << 9) + dbase) = sv;
      }
    }
  } else {
    for (int mt = 0; mt < 32; mt++) {
      const int grow = gbase + mt * 16 + ln15;
      const float* arow = (const float*)Wv + (size_t)grow * E_ + quad * 8;
      V16 areg[8];
#pragma unroll
      for (int ks = 0; ks < 8; ks++) {
        f32x4 lo = *(const f32x4*)(arow + ks * 32);
        f32x4 hi = *(const f32x4*)(arow + ks * 32 + 4);
        short8 s;
        s[0] = f2bf(lo[0]); s[1] = f2bf(lo[1]); s[2] = f2bf(lo[2]); s[3] = f2bf(lo[3]);
        s[4] = f2bf(hi[0]); s[5] = f2bf(hi[1]); s[6] = f2bf(hi[2]); s[7] = f2bf(hi[3]);
        areg[ks].s = s;
      }
      f32x4 acc[4];
#pragma unroll
      for (int nt = 0; nt < 4; nt++) acc[nt] = (f32x4){0.f, 0.f, 0.f, 0.f};
#pragma unroll
      for (int ks = 0; ks < 8; ks++)
#pragma unroll
        for (int nt = 0; nt < 4; nt++)
          acc[nt] = __builtin_amdgcn_mfma_f32_16x16x32_bf16(areg[ks].b, breg[nt][ks].b, acc[nt], 0, 0, 0);
      const int dbase = mt * 16 + quad * 4;
#pragma unroll
      for (int nt = 0; nt < 4; nt++) {
        const int batch = nt * 16 + ln15;
        s16x4 sv;
#pragma unroll
        for (int r = 0; r < 4; r++) sv[r] = f2bf(acc[nt][r]);
        *(s16x4*)((short*)xg + base_t + ((size_t)wv << 15) + ((size_t)batch << 9) + dbase) = sv;
      }
    }
  }
}

// ---------------------------------------------------------------------------
// Phase 2: persistent recurrent kernel — VERBATIM r10 (measured 1096 us;
// best of 7 protocol variants r5-r11; structural floor ~3 MALL RTs/step).
// ---------------------------------------------------------------------------
__global__ __launch_bounds__(512, 2) void lstm_kernel(
    const float* __restrict__ W_hh,
    const float* __restrict__ b_ih, const float* __restrict__ b_hh,
    const float* __restrict__ W_fc, const float* __restrict__ b_fc,
    const __hip_bfloat16* __restrict__ xg,
    unsigned int* flags, __hip_bfloat16* hbuf /*[2][64][512]*/, float* hT,
    float* out)
{
  const int tid  = threadIdx.x;
  const int blk  = blockIdx.x;
  const int g    = blk & 7;        // batch group (8 batches)
  const int pd   = blk >> 3;       // dim slice [pd*64, +64)
  const int d0   = pd * 64;
  const int wv   = tid >> 6;       // 0..7
  const int lane = tid & 63;
  const int ln15 = lane & 15, quad = lane >> 4;

  __shared__ __hip_bfloat16 s_h[16][520];   // rows 0-7: batches; 8-15: zeros
  __shared__ float s_pre[4][8][68];         // [gate][batch][dim(+4 pad)]

  const int gate  = wv >> 1;
  const int dhalf = (wv & 1) * 32;
  V16 areg[2][16];
#pragma unroll
  for (int tau = 0; tau < 2; tau++) {
    const int grow = gate * 512 + d0 + dhalf + tau * 16 + ln15;
    const float* ap = W_hh + (size_t)grow * H_ + quad * 8;
#pragma unroll
    for (int ks = 0; ks < 16; ks++) {
      f32x4 lo = *(const f32x4*)(ap + ks * 32);
      f32x4 hi = *(const f32x4*)(ap + ks * 32 + 4);
      short8 s;
      s[0] = f2bf(lo[0]); s[1] = f2bf(lo[1]); s[2] = f2bf(lo[2]); s[3] = f2bf(lo[3]);
      s[4] = f2bf(hi[0]); s[5] = f2bf(hi[1]); s[6] = f2bf(hi[2]); s[7] = f2bf(hi[3]);
      areg[tau][ks].s = s;
    }
  }

  const int nb = tid >> 6;         // 0..7  (== wv)
  const int nd = tid & 63;         // 0..63
  const int gb = g * 8 + nb;       // global batch
  const int dg = d0 + nd;          // global h-dim
  const float bias_i = b_ih[dg]        + b_hh[dg];
  const float bias_f = b_ih[512 + dg]  + b_hh[512 + dg];
  const float bias_g = b_ih[1024 + dg] + b_hh[1024 + dg];
  const float bias_o = b_ih[1536 + dg] + b_hh[1536 + dg];
  float c = 0.0f;
  const int myflag = g * 16 + pd;

  *(f32x4*)&s_h[8 + (tid >> 6)][(tid & 63) * 8] = (f32x4){0.f, 0.f, 0.f, 0.f};

  for (int t = 0; t < T_; t++) {
    const int cur = t & 1, nxt = cur ^ 1;

    const size_t xoff = (size_t)t * (G4_ * B_) + ((size_t)gb << 9) + dg;
    const __hip_bfloat16 xgi = xg[xoff];
    const __hip_bfloat16 xgf = xg[xoff + (1u << 15)];
    const __hip_bfloat16 xgg = xg[xoff + (2u << 15)];
    const __hip_bfloat16 xgo = xg[xoff + (3u << 15)];

    if (tid < 8) {
      const unsigned* fp = flags + g * 16 + tid;
      while (__hip_atomic_load(fp, __ATOMIC_RELAXED, __HIP_MEMORY_SCOPE_AGENT) < (unsigned)t) {}
    }
    __syncthreads();   // S1: h_t visible

    {
      const short* hbase = (const short*)hbuf + (size_t)cur * (B_ * H_) + (size_t)(g * 8) * H_;
      f32x4 va = ld_b128_llc(hbase + tid * 8);
      *(f32x4*)&s_h[tid >> 6][(tid & 63) * 8] = va;
    }
    __syncthreads();   // S2: LDS staging complete

    f32x4 acc0 = (f32x4){0.f, 0.f, 0.f, 0.f};
    f32x4 acc1 = (f32x4){0.f, 0.f, 0.f, 0.f};
#pragma unroll
    for (int ks = 0; ks < 16; ks++) {
      V16 b0;
      b0.f = *(const f32x4*)&s_h[ln15][quad * 8 + ks * 32];
      acc0 = __builtin_amdgcn_mfma_f32_16x16x32_bf16(areg[0][ks].b, b0.b, acc0, 0, 0, 0);
      acc1 = __builtin_amdgcn_mfma_f32_16x16x32_bf16(areg[1][ks].b, b0.b, acc1, 0, 0, 0);
    }

    if (ln15 < 8) {
      *(f32x4*)&s_pre[gate][ln15][dhalf + quad * 4]      = acc0;
      *(f32x4*)&s_pre[gate][ln15][dhalf + 16 + quad * 4] = acc1;
    }
    __syncthreads();   // S3: preactivations complete

    {
      const float pi = s_pre[0][nb][nd] + bias_i + __bfloat162float(xgi);
      const float pf = s_pre[1][nb][nd] + bias_f + __bfloat162float(xgf);
      const float pg = s_pre[2][nb][nd] + bias_g + __bfloat162float(xgg);
      const float po = s_pre[3][nb][nd] + bias_o + __bfloat162float(xgo);
      const float i_ = sigmoid_(pi), f_ = sigmoid_(pf);
      const float g_ = tanh_(pg),    o_ = sigmoid_(po);
      c = f_ * c + i_ * g_;
      const float h = o_ * tanh_(c);
      if (t < T_ - 1) {
        store_short_llc((short*)hbuf + (size_t)nxt * (B_ * H_) + (size_t)gb * H_ + dg,
                        (unsigned)(unsigned short)f2bf(h));
      } else {
        store_dword_llc(hT + gb * H_ + dg, h);
      }
    }
    __syncthreads();   // S4: vmcnt(0) drain -> h stores acked at MALL

    if (tid == 0)
      __hip_atomic_store(&flags[myflag], (unsigned)(t + 1),
                         __ATOMIC_RELAXED, __HIP_MEMORY_SCOPE_AGENT);
  }

  // Phase 3: fp32 FC by block 0
  if (blk == 0) {
    if (tid < 64)
      while (__hip_atomic_load(flags + (tid >> 3) * 16 + (tid & 7),
                               __ATOMIC_RELAXED, __HIP_MEMORY_SCOPE_AGENT) < (unsigned)T_) {}
    __builtin_amdgcn_fence(__ATOMIC_ACQUIRE, "agent");
    __syncthreads();
    for (int o = tid; o < B_ * C_; o += 512) {
      const int b = o >> 2, cl = o & 3;
      const f32x4* hr = (const f32x4*)(hT + b * H_);
      const f32x4* wr = (const f32x4*)(W_fc + cl * H_);
      float s = 0.f;
      for (int d4 = 0; d4 < H_ / 4; d4++) {
        const f32x4 hv = hr[d4];
        const f32x4 wv4 = wr[d4];
        s += hv[0] * wv4[0] + hv[1] * wv4[1] + hv[2] * wv4[2] + hv[3] * wv4[3];
      }
      s += b_fc[cl];
      out[o] = s;
    }
  }
}

// ---------------------------------------------------------------------------
// Workspace map:
//   [0, 1024)            : flags[256] (group g's 8 flags at words [g*16,+8))
//   [4096, 135168)       : hbuf[2][64][512] bf16 (zeroed = h0)
//   [135168, 266240)     : hT[64][512] fp32
//   [524288, 134742016)  : xg[T][4][B][512] bf16 (128 MiB)
//   [134742016, 135790592): W_ih bf16 table (1 MiB) — only if ws_size allows
// ---------------------------------------------------------------------------
extern "C" void kernel_launch(void* const* d_in, const int* in_sizes, int n_in,
                              void* d_out, int out_size, void* d_ws, size_t ws_size,
                              hipStream_t stream) {
  const int*   x    = (const int*)d_in[0];
  const float* emb  = (const float*)d_in[1];
  const float* W_ih = (const float*)d_in[2];
  const float* W_hh = (const float*)d_in[3];
  const float* b_ih = (const float*)d_in[4];
  const float* b_hh = (const float*)d_in[5];
  const float* W_fc = (const float*)d_in[6];
  const float* b_fc = (const float*)d_in[7];
  float* out = (float*)d_out;

  char* ws = (char*)d_ws;
  const size_t XG_OFF  = 524288;
  const size_t XG_END  = XG_OFF + (size_t)T_ * G4_ * B_ * 2;   // 134,742,016
  const size_t NEEDED2 = XG_END + (size_t)G4_ * E_ * 2;        // +1 MiB bf16 W_ih
  if (ws_size < XG_END) return;

  unsigned int*   flags = (unsigned int*)ws;
  __hip_bfloat16* hbuf  = (__hip_bfloat16*)(ws + 4096);
  float*          hT    = (float*)(ws + 135168);
  __hip_bfloat16* xg    = (__hip_bfloat16*)(ws + XG_OFF);
  short*          wih16 = (short*)(ws + XG_END);

  (void)hipMemsetAsync(ws, 0, 135168, stream);

  if (ws_size >= NEEDED2) {
    wih_conv<<<512, 256, 0, stream>>>(W_ih, wih16);
    xg_kernel<true><<<T_, 256, 0, stream>>>(x, emb, wih16, xg);
  } else {
    xg_kernel<false><<<T_, 256, 0, stream>>>(x, emb, W_ih, xg);
  }
  lstm_kernel<<<64, 512, 0, stream>>>(W_hh, b_ih, b_hh, W_fc, b_fc, xg,
                                      flags, hbuf, hT, out);
}

// Round 13
// 1269.133 us; speedup vs baseline: 1.5397x; 1.1905x over previous
//
#include <hip/hip_runtime.h>
#include <hip/hip_bf16.h>

// Problem constants
#define B_  64
#define T_  512
#define E_  256
#define H_  512
#define G4_ 2048
#define C_  4

typedef __attribute__((ext_vector_type(4))) float  f32x4;
typedef __attribute__((ext_vector_type(8))) __bf16 bf16x8;
typedef __attribute__((ext_vector_type(8))) short  short8;   // no HIP builtin 'short8'
typedef __attribute__((ext_vector_type(4))) short  s16x4;    // HIP predefines 'short4'

union V16 { f32x4 f; bf16x8 b; short8 s; };

__device__ __forceinline__ float sigmoid_(float x) { return 1.0f / (1.0f + __expf(-x)); }
__device__ __forceinline__ float tanh_(float x)    { return 1.0f - 2.0f / (__expf(2.0f * x) + 1.0f); }

// Deterministic RNE fp32 -> bf16
__device__ __forceinline__ short f2bf(float f) {
  union { float f; unsigned u; } v; v.f = f;
  return (short)((v.u + 0x7FFFu + ((v.u >> 16) & 1u)) >> 16);
}

// --- per-access MALL-coherent ops (sc0 sc1 = bypass L1+L2, coherent point) ---
__device__ __forceinline__ void store_short_llc(void* p, unsigned v) {
  asm volatile("global_store_short %0, %1, off sc0 sc1" :: "v"(p), "v"(v) : "memory");
}
__device__ __forceinline__ void store_dword_llc(void* p, float v) {
  asm volatile("global_store_dword %0, %1, off sc0 sc1" :: "v"(p), "v"(v) : "memory");
}
// one coherent 16B load + drain (staging)
__device__ __forceinline__ f32x4 ld_b128_llc(const void* p) {
  f32x4 v;
  asm volatile("global_load_dwordx4 %0, %1, off sc0 sc1\n\ts_waitcnt vmcnt(0)"
               : "=&v"(v) : "v"(p) : "memory");
  return v;
}

// ---------------------------------------------------------------------------
// One-time W_ih fp32 -> bf16 converter (r9 win).
// ---------------------------------------------------------------------------
__global__ __launch_bounds__(256, 1) void wih_conv(const float* __restrict__ W,
                                                   short* __restrict__ out) {
  const int i = (blockIdx.x * 256 + threadIdx.x) * 4;   // grid 512 -> 524288 elems
  f32x4 v = *(const f32x4*)(W + i);
  s16x4 s;
  s[0] = f2bf(v[0]); s[1] = f2bf(v[1]); s[2] = f2bf(v[2]); s[3] = f2bf(v[3]);
  *(s16x4*)(out + i) = s;
}

// ---------------------------------------------------------------------------
// Phase 1: xg[t][g][b][d] = (emb[x[b][t]] @ W_ih^T)[g*512+d]  (bias added later)
// r13: A-fragment double buffer with STATIC indexing (r12's runtime-indexed
// areg[cb][ks] was demoted to scratch — the "pipelining" was actually
// spill-reload). mt-loop unrolled x2 with named buffers a0/a1; tile mt+1's 8
// L2 loads issue ahead of tile mt's 32 MFMAs, so vmcnt waits overlap compute.
// ---------------------------------------------------------------------------
template<bool WBF16>
__global__ __launch_bounds__(256, 1) void xg_kernel(
    const int* __restrict__ x, const float* __restrict__ emb,
    const void* __restrict__ Wv,
    __hip_bfloat16* __restrict__ xg)
{
  const int t   = blockIdx.x;
  const int tid = threadIdx.x;
  __shared__ int s_idx[B_];
  __shared__ __hip_bfloat16 s_e[B_][E_ + 8];

  if (tid < B_) s_idx[tid] = x[tid * T_ + t];
  __syncthreads();
  {
    int b = tid >> 2, ch = tid & 3;
    const float* src = emb + (size_t)s_idx[b] * E_ + ch * 64;
    short* dst = (short*)&s_e[b][ch * 64];
#pragma unroll
    for (int i = 0; i < 16; i++) {
      f32x4 v = *(const f32x4*)(src + i * 4);
      s16x4 s;
      s[0] = f2bf(v[0]); s[1] = f2bf(v[1]); s[2] = f2bf(v[2]); s[3] = f2bf(v[3]);
      *(s16x4*)(dst + i * 4) = s;
    }
  }
  __syncthreads();

  const int wv   = tid >> 6;
  const int lane = tid & 63;
  const int ln15 = lane & 15, quad = lane >> 4;

  V16 breg[4][8];
#pragma unroll
  for (int nt = 0; nt < 4; nt++)
#pragma unroll
    for (int ks = 0; ks < 8; ks++)
      breg[nt][ks].f = *(const f32x4*)(&s_e[nt * 16 + ln15][quad * 8 + ks * 32]);

  const int gbase = wv * 512;
  const size_t base_t = (size_t)t * (G4_ * B_);

  if constexpr (WBF16) {
    const short* W16 = (const short*)Wv;
    const short* wbase = W16 + (size_t)(gbase + ln15) * E_ + quad * 8;
    const size_t mstride = (size_t)16 * E_;          // 16 gate rows per M-tile
    V16 a0[8], a1[8];

#pragma unroll
    for (int ks = 0; ks < 8; ks++)                   // tile 0
      a0[ks].f = *(const f32x4*)(wbase + ks * 32);

    for (int mt = 0; mt < 32; mt += 2) {
      // prefetch tile mt+1 (overlaps tile mt's MFMAs below)
      const short* w1 = wbase + (size_t)(mt + 1) * mstride;
#pragma unroll
      for (int ks = 0; ks < 8; ks++)
        a1[ks].f = *(const f32x4*)(w1 + ks * 32);

      {
        f32x4 acc[4];
#pragma unroll
        for (int nt = 0; nt < 4; nt++) acc[nt] = (f32x4){0.f, 0.f, 0.f, 0.f};
#pragma unroll
        for (int ks = 0; ks < 8; ks++)
#pragma unroll
          for (int nt = 0; nt < 4; nt++)
            acc[nt] = __builtin_amdgcn_mfma_f32_16x16x32_bf16(a0[ks].b, breg[nt][ks].b, acc[nt], 0, 0, 0);
        const int dbase = mt * 16 + quad * 4;
#pragma unroll
        for (int nt = 0; nt < 4; nt++) {
          const int batch = nt * 16 + ln15;
          s16x4 sv;
#pragma unroll
          for (int r = 0; r < 4; r++) sv[r] = f2bf(acc[nt][r]);
          *(s16x4*)((short*)xg + base_t + ((size_t)wv << 15) + ((size_t)batch << 9) + dbase) = sv;
        }
      }

      // prefetch tile mt+2 (overlaps tile mt+1's MFMAs)
      if (mt < 30) {
        const short* w2 = wbase + (size_t)(mt + 2) * mstride;
#pragma unroll
        for (int ks = 0; ks < 8; ks++)
          a0[ks].f = *(const f32x4*)(w2 + ks * 32);
      }

      {
        f32x4 acc[4];
#pragma unroll
        for (int nt = 0; nt < 4; nt++) acc[nt] = (f32x4){0.f, 0.f, 0.f, 0.f};
#pragma unroll
        for (int ks = 0; ks < 8; ks++)
#pragma unroll
          for (int nt = 0; nt < 4; nt++)
            acc[nt] = __builtin_amdgcn_mfma_f32_16x16x32_bf16(a1[ks].b, breg[nt][ks].b, acc[nt], 0, 0, 0);
        const int dbase = (mt + 1) * 16 + quad * 4;
#pragma unroll
        for (int nt = 0; nt < 4; nt++) {
          const int batch = nt * 16 + ln15;
          s16x4 sv;
#pragma unroll
          for (int r = 0; r < 4; r++) sv[r] = f2bf(acc[nt][r]);
          *(s16x4*)((short*)xg + base_t + ((size_t)wv << 15) + ((size_t)batch << 9) + dbase) = sv;
        }
      }
    }
  } else {
    for (int mt = 0; mt < 32; mt++) {
      const int grow = gbase + mt * 16 + ln15;
      const float* arow = (const float*)Wv + (size_t)grow * E_ + quad * 8;
      V16 areg[8];
#pragma unroll
      for (int ks = 0; ks < 8; ks++) {
        f32x4 lo = *(const f32x4*)(arow + ks * 32);
        f32x4 hi = *(const f32x4*)(arow + ks * 32 + 4);
        short8 s;
        s[0] = f2bf(lo[0]); s[1] = f2bf(lo[1]); s[2] = f2bf(lo[2]); s[3] = f2bf(lo[3]);
        s[4] = f2bf(hi[0]); s[5] = f2bf(hi[1]); s[6] = f2bf(hi[2]); s[7] = f2bf(hi[3]);
        areg[ks].s = s;
      }
      f32x4 acc[4];
#pragma unroll
      for (int nt = 0; nt < 4; nt++) acc[nt] = (f32x4){0.f, 0.f, 0.f, 0.f};
#pragma unroll
      for (int ks = 0; ks < 8; ks++)
#pragma unroll
        for (int nt = 0; nt < 4; nt++)
          acc[nt] = __builtin_amdgcn_mfma_f32_16x16x32_bf16(areg[ks].b, breg[nt][ks].b, acc[nt], 0, 0, 0);
      const int dbase = mt * 16 + quad * 4;
#pragma unroll
      for (int nt = 0; nt < 4; nt++) {
        const int batch = nt * 16 + ln15;
        s16x4 sv;
#pragma unroll
        for (int r = 0; r < 4; r++) sv[r] = f2bf(acc[nt][r]);
        *(s16x4*)((short*)xg + base_t + ((size_t)wv << 15) + ((size_t)batch << 9) + dbase) = sv;
      }
    }
  }
}

// ---------------------------------------------------------------------------
// Phase 2: persistent recurrent kernel — VERBATIM r10 (measured 1086-1096 us;
// best of 7 protocol variants r5-r11; structural floor ~3 MALL RTs/step).
// ---------------------------------------------------------------------------
__global__ __launch_bounds__(512, 2) void lstm_kernel(
    const float* __restrict__ W_hh,
    const float* __restrict__ b_ih, const float* __restrict__ b_hh,
    const float* __restrict__ W_fc, const float* __restrict__ b_fc,
    const __hip_bfloat16* __restrict__ xg,
    unsigned int* flags, __hip_bfloat16* hbuf /*[2][64][512]*/, float* hT,
    float* out)
{
  const int tid  = threadIdx.x;
  const int blk  = blockIdx.x;
  const int g    = blk & 7;        // batch group (8 batches)
  const int pd   = blk >> 3;       // dim slice [pd*64, +64)
  const int d0   = pd * 64;
  const int wv   = tid >> 6;       // 0..7
  const int lane = tid & 63;
  const int ln15 = lane & 15, quad = lane >> 4;

  __shared__ __hip_bfloat16 s_h[16][520];   // rows 0-7: batches; 8-15: zeros
  __shared__ float s_pre[4][8][68];         // [gate][batch][dim(+4 pad)]

  const int gate  = wv >> 1;
  const int dhalf = (wv & 1) * 32;
  V16 areg[2][16];
#pragma unroll
  for (int tau = 0; tau < 2; tau++) {
    const int grow = gate * 512 + d0 + dhalf + tau * 16 + ln15;
    const float* ap = W_hh + (size_t)grow * H_ + quad * 8;
#pragma unroll
    for (int ks = 0; ks < 16; ks++) {
      f32x4 lo = *(const f32x4*)(ap + ks * 32);
      f32x4 hi = *(const f32x4*)(ap + ks * 32 + 4);
      short8 s;
      s[0] = f2bf(lo[0]); s[1] = f2bf(lo[1]); s[2] = f2bf(lo[2]); s[3] = f2bf(lo[3]);
      s[4] = f2bf(hi[0]); s[5] = f2bf(hi[1]); s[6] = f2bf(hi[2]); s[7] = f2bf(hi[3]);
      areg[tau][ks].s = s;
    }
  }

  const int nb = tid >> 6;         // 0..7  (== wv)
  const int nd = tid & 63;         // 0..63
  const int gb = g * 8 + nb;       // global batch
  const int dg = d0 + nd;          // global h-dim
  const float bias_i = b_ih[dg]        + b_hh[dg];
  const float bias_f = b_ih[512 + dg]  + b_hh[512 + dg];
  const float bias_g = b_ih[1024 + dg] + b_hh[1024 + dg];
  const float bias_o = b_ih[1536 + dg] + b_hh[1536 + dg];
  float c = 0.0f;
  const int myflag = g * 16 + pd;

  *(f32x4*)&s_h[8 + (tid >> 6)][(tid & 63) * 8] = (f32x4){0.f, 0.f, 0.f, 0.f};

  for (int t = 0; t < T_; t++) {
    const int cur = t & 1, nxt = cur ^ 1;

    const size_t xoff = (size_t)t * (G4_ * B_) + ((size_t)gb << 9) + dg;
    const __hip_bfloat16 xgi = xg[xoff];
    const __hip_bfloat16 xgf = xg[xoff + (1u << 15)];
    const __hip_bfloat16 xgg = xg[xoff + (2u << 15)];
    const __hip_bfloat16 xgo = xg[xoff + (3u << 15)];

    if (tid < 8) {
      const unsigned* fp = flags + g * 16 + tid;
      while (__hip_atomic_load(fp, __ATOMIC_RELAXED, __HIP_MEMORY_SCOPE_AGENT) < (unsigned)t) {}
    }
    __syncthreads();   // S1: h_t visible

    {
      const short* hbase = (const short*)hbuf + (size_t)cur * (B_ * H_) + (size_t)(g * 8) * H_;
      f32x4 va = ld_b128_llc(hbase + tid * 8);
      *(f32x4*)&s_h[tid >> 6][(tid & 63) * 8] = va;
    }
    __syncthreads();   // S2: LDS staging complete

    f32x4 acc0 = (f32x4){0.f, 0.f, 0.f, 0.f};
    f32x4 acc1 = (f32x4){0.f, 0.f, 0.f, 0.f};
#pragma unroll
    for (int ks = 0; ks < 16; ks++) {
      V16 b0;
      b0.f = *(const f32x4*)&s_h[ln15][quad * 8 + ks * 32];
      acc0 = __builtin_amdgcn_mfma_f32_16x16x32_bf16(areg[0][ks].b, b0.b, acc0, 0, 0, 0);
      acc1 = __builtin_amdgcn_mfma_f32_16x16x32_bf16(areg[1][ks].b, b0.b, acc1, 0, 0, 0);
    }

    if (ln15 < 8) {
      *(f32x4*)&s_pre[gate][ln15][dhalf + quad * 4]      = acc0;
      *(f32x4*)&s_pre[gate][ln15][dhalf + 16 + quad * 4] = acc1;
    }
    __syncthreads();   // S3: preactivations complete

    {
      const float pi = s_pre[0][nb][nd] + bias_i + __bfloat162float(xgi);
      const float pf = s_pre[1][nb][nd] + bias_f + __bfloat162float(xgf);
      const float pg = s_pre[2][nb][nd] + bias_g + __bfloat162float(xgg);
      const float po = s_pre[3][nb][nd] + bias_o + __bfloat162float(xgo);
      const float i_ = sigmoid_(pi), f_ = sigmoid_(pf);
      const float g_ = tanh_(pg),    o_ = sigmoid_(po);
      c = f_ * c + i_ * g_;
      const float h = o_ * tanh_(c);
      if (t < T_ - 1) {
        store_short_llc((short*)hbuf + (size_t)nxt * (B_ * H_) + (size_t)gb * H_ + dg,
                        (unsigned)(unsigned short)f2bf(h));
      } else {
        store_dword_llc(hT + gb * H_ + dg, h);
      }
    }
    __syncthreads();   // S4: vmcnt(0) drain -> h stores acked at MALL

    if (tid == 0)
      __hip_atomic_store(&flags[myflag], (unsigned)(t + 1),
                         __ATOMIC_RELAXED, __HIP_MEMORY_SCOPE_AGENT);
  }

  // Phase 3: fp32 FC by block 0
  if (blk == 0) {
    if (tid < 64)
      while (__hip_atomic_load(flags + (tid >> 3) * 16 + (tid & 7),
                               __ATOMIC_RELAXED, __HIP_MEMORY_SCOPE_AGENT) < (unsigned)T_) {}
    __builtin_amdgcn_fence(__ATOMIC_ACQUIRE, "agent");
    __syncthreads();
    for (int o = tid; o < B_ * C_; o += 512) {
      const int b = o >> 2, cl = o & 3;
      const f32x4* hr = (const f32x4*)(hT + b * H_);
      const f32x4* wr = (const f32x4*)(W_fc + cl * H_);
      float s = 0.f;
      for (int d4 = 0; d4 < H_ / 4; d4++) {
        const f32x4 hv = hr[d4];
        const f32x4 wv4 = wr[d4];
        s += hv[0] * wv4[0] + hv[1] * wv4[1] + hv[2] * wv4[2] + hv[3] * wv4[3];
      }
      s += b_fc[cl];
      out[o] = s;
    }
  }
}

// ---------------------------------------------------------------------------
// Workspace map:
//   [0, 1024)            : flags[256] (group g's 8 flags at words [g*16,+8))
//   [4096, 135168)       : hbuf[2][64][512] bf16 (zeroed = h0)
//   [135168, 266240)     : hT[64][512] fp32
//   [524288, 134742016)  : xg[T][4][B][512] bf16 (128 MiB)
//   [134742016, 135790592): W_ih bf16 table (1 MiB) — only if ws_size allows
// ---------------------------------------------------------------------------
extern "C" void kernel_launch(void* const* d_in, const int* in_sizes, int n_in,
                              void* d_out, int out_size, void* d_ws, size_t ws_size,
                              hipStream_t stream) {
  const int*   x    = (const int*)d_in[0];
  const float* emb  = (const float*)d_in[1];
  const float* W_ih = (const float*)d_in[2];
  const float* W_hh = (const float*)d_in[3];
  const float* b_ih = (const float*)d_in[4];
  const float* b_hh = (const float*)d_in[5];
  const float* W_fc = (const float*)d_in[6];
  const float* b_fc = (const float*)d_in[7];
  float* out = (float*)d_out;

  char* ws = (char*)d_ws;
  const size_t XG_OFF  = 524288;
  const size_t XG_END  = XG_OFF + (size_t)T_ * G4_ * B_ * 2;   // 134,742,016
  const size_t NEEDED2 = XG_END + (size_t)G4_ * E_ * 2;        // +1 MiB bf16 W_ih
  if (ws_size < XG_END) return;

  unsigned int*   flags = (unsigned int*)ws;
  __hip_bfloat16* hbuf  = (__hip_bfloat16*)(ws + 4096);
  float*          hT    = (float*)(ws + 135168);
  __hip_bfloat16* xg    = (__hip_bfloat16*)(ws + XG_OFF);
  short*          wih16 = (short*)(ws + XG_END);

  (void)hipMemsetAsync(ws, 0, 135168, stream);

  if (ws_size >= NEEDED2) {
    wih_conv<<<512, 256, 0, stream>>>(W_ih, wih16);
    xg_kernel<true><<<T_, 256, 0, stream>>>(x, emb, wih16, xg);
  } else {
    xg_kernel<false><<<T_, 256, 0, stream>>>(x, emb, W_ih, xg);
  }
  lstm_kernel<<<64, 512, 0, stream>>>(W_hh, b_ih, b_hh, W_fc, b_fc, xg,
                                      flags, hbuf, hT, out);
}

// Round 14
// 1235.406 us; speedup vs baseline: 1.5817x; 1.0273x over previous
//
#include <hip/hip_runtime.h>
#include <hip/hip_bf16.h>

// Problem constants
#define B_  64
#define T_  512
#define E_  256
#define H_  512
#define G4_ 2048
#define C_  4

typedef __attribute__((ext_vector_type(4))) float  f32x4;
typedef __attribute__((ext_vector_type(8))) __bf16 bf16x8;
typedef __attribute__((ext_vector_type(8))) short  short8;   // no HIP builtin 'short8'
typedef __attribute__((ext_vector_type(4))) short  s16x4;    // HIP predefines 'short4'

union V16 { f32x4 f; bf16x8 b; short8 s; };

__device__ __forceinline__ float sigmoid_(float x) { return 1.0f / (1.0f + __expf(-x)); }
__device__ __forceinline__ float tanh_(float x)    { return 1.0f - 2.0f / (__expf(2.0f * x) + 1.0f); }

// Deterministic RNE fp32 -> bf16
__device__ __forceinline__ short f2bf(float f) {
  union { float f; unsigned u; } v; v.f = f;
  return (short)((v.u + 0x7FFFu + ((v.u >> 16) & 1u)) >> 16);
}

// --- per-access MALL-coherent ops (sc0 sc1 = bypass L1+L2, coherent point) ---
__device__ __forceinline__ void store_short_llc(void* p, unsigned v) {
  asm volatile("global_store_short %0, %1, off sc0 sc1" :: "v"(p), "v"(v) : "memory");
}
__device__ __forceinline__ void store_dword_llc(void* p, float v) {
  asm volatile("global_store_dword %0, %1, off sc0 sc1" :: "v"(p), "v"(v) : "memory");
}
// one coherent 16B load + drain (staging)
__device__ __forceinline__ f32x4 ld_b128_llc(const void* p) {
  f32x4 v;
  asm volatile("global_load_dwordx4 %0, %1, off sc0 sc1\n\ts_waitcnt vmcnt(0)"
               : "=&v"(v) : "v"(p) : "memory");
  return v;
}

// ---------------------------------------------------------------------------
// One-time W_ih fp32 -> bf16 converter (r9 win).
// ---------------------------------------------------------------------------
__global__ __launch_bounds__(256, 1) void wih_conv(const float* __restrict__ W,
                                                   short* __restrict__ out) {
  const int i = (blockIdx.x * 256 + threadIdx.x) * 4;   // grid 512 -> 524288 elems
  f32x4 v = *(const f32x4*)(W + i);
  s16x4 s;
  s[0] = f2bf(v[0]); s[1] = f2bf(v[1]); s[2] = f2bf(v[2]); s[3] = f2bf(v[3]);
  *(s16x4*)(out + i) = s;
}

// ---------------------------------------------------------------------------
// Phase 1: xg[t][g][b][d] = (emb[x[b][t]] @ W_ih^T)[g*512+d]  (bias added later)
// r14: COALESCED C-WRITE. r13 showed xg is not load-latency-bound; 128 MiB at
// 1.07 TB/s with 32B store segments says write efficiency is the binder.
// Each wave stages 8 M-tiles (128 dims x 64 batches) in a wave-private LDS
// buffer (pad 136 -> 2-way bank aliasing only), then drains with b128 stores
// where lanes 0-15 cover one batch row's 256 B contiguously (4 x 256B
// segments/inst vs 16 x 32B). Same values, same addresses -> bitwise output.
// A-loads reverted to r10's simple per-tile loads (r13 dbuf was neutral).
// ---------------------------------------------------------------------------
union XgSmem {
  struct { int idx[B_]; short e[B_][E_ + 8]; } g;   // gather phase (34 KB)
  short o[4][64][136];                              // epilogue staging (68 KB)
};

template<bool WBF16>
__global__ __launch_bounds__(256, 2) void xg_kernel(
    const int* __restrict__ x, const float* __restrict__ emb,
    const void* __restrict__ Wv,
    __hip_bfloat16* __restrict__ xg)
{
  const int t   = blockIdx.x;
  const int tid = threadIdx.x;
  __shared__ XgSmem sm;

  if (tid < B_) sm.g.idx[tid] = x[tid * T_ + t];
  __syncthreads();
  {
    int b = tid >> 2, ch = tid & 3;
    const float* src = emb + (size_t)sm.g.idx[b] * E_ + ch * 64;
    short* dst = &sm.g.e[b][ch * 64];
#pragma unroll
    for (int i = 0; i < 16; i++) {
      f32x4 v = *(const f32x4*)(src + i * 4);
      s16x4 s;
      s[0] = f2bf(v[0]); s[1] = f2bf(v[1]); s[2] = f2bf(v[2]); s[3] = f2bf(v[3]);
      *(s16x4*)(dst + i * 4) = s;
    }
  }
  __syncthreads();

  const int wv   = tid >> 6;
  const int lane = tid & 63;
  const int ln15 = lane & 15, quad = lane >> 4;

  // B operand fully captured in registers; s_e is dead after this.
  V16 breg[4][8];
#pragma unroll
  for (int nt = 0; nt < 4; nt++)
#pragma unroll
    for (int ks = 0; ks < 8; ks++)
      breg[nt][ks].f = *(const f32x4*)(&sm.g.e[nt * 16 + ln15][quad * 8 + ks * 32]);
  __syncthreads();   // all waves done reading s_e before s_o overwrites it

  const int gbase = wv * 512;
  const size_t base_t = (size_t)t * (G4_ * B_);

  for (int q = 0; q < 4; q++) {          // quarter = 8 M-tiles = dims [q*128,+128)
#pragma unroll
    for (int m8 = 0; m8 < 8; m8++) {
      const int mt = q * 8 + m8;
      V16 areg[8];
      if constexpr (WBF16) {
        const short* arow = (const short*)Wv + (size_t)(gbase + mt * 16 + ln15) * E_ + quad * 8;
#pragma unroll
        for (int ks = 0; ks < 8; ks++)
          areg[ks].f = *(const f32x4*)(arow + ks * 32);
      } else {
        const float* arow = (const float*)Wv + (size_t)(gbase + mt * 16 + ln15) * E_ + quad * 8;
#pragma unroll
        for (int ks = 0; ks < 8; ks++) {
          f32x4 lo = *(const f32x4*)(arow + ks * 32);
          f32x4 hi = *(const f32x4*)(arow + ks * 32 + 4);
          short8 s;
          s[0] = f2bf(lo[0]); s[1] = f2bf(lo[1]); s[2] = f2bf(lo[2]); s[3] = f2bf(lo[3]);
          s[4] = f2bf(hi[0]); s[5] = f2bf(hi[1]); s[6] = f2bf(hi[2]); s[7] = f2bf(hi[3]);
          areg[ks].s = s;
        }
      }

      f32x4 acc[4];
#pragma unroll
      for (int nt = 0; nt < 4; nt++) acc[nt] = (f32x4){0.f, 0.f, 0.f, 0.f};
#pragma unroll
      for (int ks = 0; ks < 8; ks++)
#pragma unroll
        for (int nt = 0; nt < 4; nt++)
          acc[nt] = __builtin_amdgcn_mfma_f32_16x16x32_bf16(areg[ks].b, breg[nt][ks].b, acc[nt], 0, 0, 0);

      // stage C tile into wave-private LDS (2-way bank aliasing only)
      const int dl = m8 * 16 + quad * 4;
#pragma unroll
      for (int nt = 0; nt < 4; nt++) {
        const int batch = nt * 16 + ln15;
        s16x4 sv;
#pragma unroll
        for (int r = 0; r < 4; r++) sv[r] = f2bf(acc[nt][r]);
        *(s16x4*)&sm.o[wv][batch][dl] = sv;
      }
    }

    // drain quarter: 16 b128 insts; lanes 0-15 = one batch row's 256 B
    const size_t qbase = base_t + ((size_t)wv << 15) + q * 128;
    const int chunk = lane & 15;
#pragma unroll
    for (int i = 0; i < 16; i++) {
      const int row = (lane >> 4) + i * 4;
      f32x4 v = *(const f32x4*)&sm.o[wv][row][chunk * 8];
      *(f32x4*)((short*)xg + qbase + ((size_t)row << 9) + chunk * 8) = v;
    }
  }
}

// ---------------------------------------------------------------------------
// Phase 2: persistent recurrent kernel — VERBATIM r10 (measured 1086-1096 us;
// best of 8 protocol variants r5-r11; structural floor ~3 MALL RTs/step).
// ---------------------------------------------------------------------------
__global__ __launch_bounds__(512, 2) void lstm_kernel(
    const float* __restrict__ W_hh,
    const float* __restrict__ b_ih, const float* __restrict__ b_hh,
    const float* __restrict__ W_fc, const float* __restrict__ b_fc,
    const __hip_bfloat16* __restrict__ xg,
    unsigned int* flags, __hip_bfloat16* hbuf /*[2][64][512]*/, float* hT,
    float* out)
{
  const int tid  = threadIdx.x;
  const int blk  = blockIdx.x;
  const int g    = blk & 7;        // batch group (8 batches)
  const int pd   = blk >> 3;       // dim slice [pd*64, +64)
  const int d0   = pd * 64;
  const int wv   = tid >> 6;       // 0..7
  const int lane = tid & 63;
  const int ln15 = lane & 15, quad = lane >> 4;

  __shared__ __hip_bfloat16 s_h[16][520];   // rows 0-7: batches; 8-15: zeros
  __shared__ float s_pre[4][8][68];         // [gate][batch][dim(+4 pad)]

  const int gate  = wv >> 1;
  const int dhalf = (wv & 1) * 32;
  V16 areg[2][16];
#pragma unroll
  for (int tau = 0; tau < 2; tau++) {
    const int grow = gate * 512 + d0 + dhalf + tau * 16 + ln15;
    const float* ap = W_hh + (size_t)grow * H_ + quad * 8;
#pragma unroll
    for (int ks = 0; ks < 16; ks++) {
      f32x4 lo = *(const f32x4*)(ap + ks * 32);
      f32x4 hi = *(const f32x4*)(ap + ks * 32 + 4);
      short8 s;
      s[0] = f2bf(lo[0]); s[1] = f2bf(lo[1]); s[2] = f2bf(lo[2]); s[3] = f2bf(lo[3]);
      s[4] = f2bf(hi[0]); s[5] = f2bf(hi[1]); s[6] = f2bf(hi[2]); s[7] = f2bf(hi[3]);
      areg[tau][ks].s = s;
    }
  }

  const int nb = tid >> 6;         // 0..7  (== wv)
  const int nd = tid & 63;         // 0..63
  const int gb = g * 8 + nb;       // global batch
  const int dg = d0 + nd;          // global h-dim
  const float bias_i = b_ih[dg]        + b_hh[dg];
  const float bias_f = b_ih[512 + dg]  + b_hh[512 + dg];
  const float bias_g = b_ih[1024 + dg] + b_hh[1024 + dg];
  const float bias_o = b_ih[1536 + dg] + b_hh[1536 + dg];
  float c = 0.0f;
  const int myflag = g * 16 + pd;

  *(f32x4*)&s_h[8 + (tid >> 6)][(tid & 63) * 8] = (f32x4){0.f, 0.f, 0.f, 0.f};

  for (int t = 0; t < T_; t++) {
    const int cur = t & 1, nxt = cur ^ 1;

    const size_t xoff = (size_t)t * (G4_ * B_) + ((size_t)gb << 9) + dg;
    const __hip_bfloat16 xgi = xg[xoff];
    const __hip_bfloat16 xgf = xg[xoff + (1u << 15)];
    const __hip_bfloat16 xgg = xg[xoff + (2u << 15)];
    const __hip_bfloat16 xgo = xg[xoff + (3u << 15)];

    if (tid < 8) {
      const unsigned* fp = flags + g * 16 + tid;
      while (__hip_atomic_load(fp, __ATOMIC_RELAXED, __HIP_MEMORY_SCOPE_AGENT) < (unsigned)t) {}
    }
    __syncthreads();   // S1: h_t visible

    {
      const short* hbase = (const short*)hbuf + (size_t)cur * (B_ * H_) + (size_t)(g * 8) * H_;
      f32x4 va = ld_b128_llc(hbase + tid * 8);
      *(f32x4*)&s_h[tid >> 6][(tid & 63) * 8] = va;
    }
    __syncthreads();   // S2: LDS staging complete

    f32x4 acc0 = (f32x4){0.f, 0.f, 0.f, 0.f};
    f32x4 acc1 = (f32x4){0.f, 0.f, 0.f, 0.f};
#pragma unroll
    for (int ks = 0; ks < 16; ks++) {
      V16 b0;
      b0.f = *(const f32x4*)&s_h[ln15][quad * 8 + ks * 32];
      acc0 = __builtin_amdgcn_mfma_f32_16x16x32_bf16(areg[0][ks].b, b0.b, acc0, 0, 0, 0);
      acc1 = __builtin_amdgcn_mfma_f32_16x16x32_bf16(areg[1][ks].b, b0.b, acc1, 0, 0, 0);
    }

    if (ln15 < 8) {
      *(f32x4*)&s_pre[gate][ln15][dhalf + quad * 4]      = acc0;
      *(f32x4*)&s_pre[gate][ln15][dhalf + 16 + quad * 4] = acc1;
    }
    __syncthreads();   // S3: preactivations complete

    {
      const float pi = s_pre[0][nb][nd] + bias_i + __bfloat162float(xgi);
      const float pf = s_pre[1][nb][nd] + bias_f + __bfloat162float(xgf);
      const float pg = s_pre[2][nb][nd] + bias_g + __bfloat162float(xgg);
      const float po = s_pre[3][nb][nd] + bias_o + __bfloat162float(xgo);
      const float i_ = sigmoid_(pi), f_ = sigmoid_(pf);
      const float g_ = tanh_(pg),    o_ = sigmoid_(po);
      c = f_ * c + i_ * g_;
      const float h = o_ * tanh_(c);
      if (t < T_ - 1) {
        store_short_llc((short*)hbuf + (size_t)nxt * (B_ * H_) + (size_t)gb * H_ + dg,
                        (unsigned)(unsigned short)f2bf(h));
      } else {
        store_dword_llc(hT + gb * H_ + dg, h);
      }
    }
    __syncthreads();   // S4: vmcnt(0) drain -> h stores acked at MALL

    if (tid == 0)
      __hip_atomic_store(&flags[myflag], (unsigned)(t + 1),
                         __ATOMIC_RELAXED, __HIP_MEMORY_SCOPE_AGENT);
  }

  // Phase 3: fp32 FC by block 0
  if (blk == 0) {
    if (tid < 64)
      while (__hip_atomic_load(flags + (tid >> 3) * 16 + (tid & 7),
                               __ATOMIC_RELAXED, __HIP_MEMORY_SCOPE_AGENT) < (unsigned)T_) {}
    __builtin_amdgcn_fence(__ATOMIC_ACQUIRE, "agent");
    __syncthreads();
    for (int o = tid; o < B_ * C_; o += 512) {
      const int b = o >> 2, cl = o & 3;
      const f32x4* hr = (const f32x4*)(hT + b * H_);
      const f32x4* wr = (const f32x4*)(W_fc + cl * H_);
      float s = 0.f;
      for (int d4 = 0; d4 < H_ / 4; d4++) {
        const f32x4 hv = hr[d4];
        const f32x4 wv4 = wr[d4];
        s += hv[0] * wv4[0] + hv[1] * wv4[1] + hv[2] * wv4[2] + hv[3] * wv4[3];
      }
      s += b_fc[cl];
      out[o] = s;
    }
  }
}

// ---------------------------------------------------------------------------
// Workspace map:
//   [0, 1024)            : flags[256] (group g's 8 flags at words [g*16,+8))
//   [4096, 135168)       : hbuf[2][64][512] bf16 (zeroed = h0)
//   [135168, 266240)     : hT[64][512] fp32
//   [524288, 134742016)  : xg[T][4][B][512] bf16 (128 MiB)
//   [134742016, 135790592): W_ih bf16 table (1 MiB) — only if ws_size allows
// ---------------------------------------------------------------------------
extern "C" void kernel_launch(void* const* d_in, const int* in_sizes, int n_in,
                              void* d_out, int out_size, void* d_ws, size_t ws_size,
                              hipStream_t stream) {
  const int*   x    = (const int*)d_in[0];
  const float* emb  = (const float*)d_in[1];
  const float* W_ih = (const float*)d_in[2];
  const float* W_hh = (const float*)d_in[3];
  const float* b_ih = (const float*)d_in[4];
  const float* b_hh = (const float*)d_in[5];
  const float* W_fc = (const float*)d_in[6];
  const float* b_fc = (const float*)d_in[7];
  float* out = (float*)d_out;

  char* ws = (char*)d_ws;
  const size_t XG_OFF  = 524288;
  const size_t XG_END  = XG_OFF + (size_t)T_ * G4_ * B_ * 2;   // 134,742,016
  const size_t NEEDED2 = XG_END + (size_t)G4_ * E_ * 2;        // +1 MiB bf16 W_ih
  if (ws_size < XG_END) return;

  unsigned int*   flags = (unsigned int*)ws;
  __hip_bfloat16* hbuf  = (__hip_bfloat16*)(ws + 4096);
  float*          hT    = (float*)(ws + 135168);
  __hip_bfloat16* xg    = (__hip_bfloat16*)(ws + XG_OFF);
  short*          wih16 = (short*)(ws + XG_END);

  (void)hipMemsetAsync(ws, 0, 135168, stream);

  if (ws_size >= NEEDED2) {
    wih_conv<<<512, 256, 0, stream>>>(W_ih, wih16);
    xg_kernel<true><<<T_, 256, 0, stream>>>(x, emb, wih16, xg);
  } else {
    xg_kernel<false><<<T_, 256, 0, stream>>>(x, emb, W_ih, xg);
  }
  lstm_kernel<<<64, 512, 0, stream>>>(W_hh, b_ih, b_hh, W_fc, b_fc, xg,
                                      flags, hbuf, hT, out);
}